// Round 20
// baseline (136.542 us; speedup 1.0000x reference)
//
#include <hip/hip_runtime.h>

#define N_INST   1000000
#define NHALF    (N_INST / 2)
#define NBX      512
#define NBY      512
#define NB       (NBX * NBY)
#define NUM_CKSR 48
#define NUM_CE   96
#define K        4          // w[4] of the reference 5-tap is identically 0 (half = 1.5 exactly)

// R20 = R19 + classify ILP: returning atomics are LATENCY-bound (R19: fire-and-forget
// atomics in tile were free; classify's dependent atomic->store chains are the cost).
// Each thread handles 2 instances; all atomicAdds issued before any dependent store.
#define FTX   16
#define FTY   8
#define TGX   (NBX / FTX)   // 32
#define TGY   (NBY / FTY)   // 64
#define NFT   (TGX * TGY)   // 2048
#define SUB   8             // sub-buckets by blockIdx&7 (R13: single writer-XCD per line)
#define CAPL  96            // per sub-bucket; lut mean 43.6
#define CAPF  48            // per sub-bucket; ff mean 14.3 (dup 1.633)
#define RS    145           // 48 ck + 96 ce + pad (odd stride, conflict-free)
#define ACCW  (FTX * FTY * RS)      // 18560 words
#define PXW   20            // lut patch: x in [X0-2, X0+17]
#define PYW   12            // y in [Y0-2, Y0+9]
#define PW    (PXW * PYW)   // 240 cells/patch

#define CSTRIDE 16          // one cursor per 64B line (R5 lesson)

// Constants folded in DOUBLE then rounded once to f32 (matches JAX): half = 1.5f exactly.
#define KHALF  ((float)(2.5 * 0.6))
#define KDENOM ((float)(0.6 * 1.4142135623730951))

__device__ __forceinline__ void axis_weights4(float pos, int nbins, int& lo_out, float w[K]) {
    float wlo = pos - KHALF;
    float whi = pos + KHALF;
    int lo_bin = (int)floorf(wlo);
    lo_out = lo_bin;
    float phi[K + 1];
#pragma unroll
    for (int k = 0; k <= K; ++k) {
        float e = (float)(lo_bin + k);
        float ec = fminf(fmaxf(e, wlo), whi);
        phi[k] = 0.5f * (1.f + erff((ec - pos) / KDENOM));
    }
    float wsum = 0.f;
#pragma unroll
    for (int k = 0; k < K; ++k) {
        int b = lo_bin + k;
        float ww = phi[k + 1] - phi[k];
        if (b < 0 || b >= nbins) ww = 0.f;
        w[k] = ww;
        wsum += ww;
    }
    float d = wsum + 1e-12f;
#pragma unroll
    for (int k = 0; k < K; ++k) w[k] = w[k] / d;   // division, as in reference
}

__device__ __forceinline__ unsigned q10(float w) {   // plain u10 (lut path only; no ceil)
    return min(1023u, (unsigned)rintf(w * 1024.f));
}

// Pass 1: erf once; 2 instances/thread; phase-split compute -> atomics -> stores so
// up to 10 independent atomicAdds are in flight per thread.
__global__ void __launch_bounds__(256) classify_kernel(
        const float* __restrict__ pos,
        const int* __restrict__ luts,
        const int* __restrict__ ffs,
        const int* __restrict__ ctrl,
        int* __restrict__ lut_cur,        // [NFT*SUB*CSTRIDE] zeroed
        int* __restrict__ ff_cur,         // [NFT*SUB*CSTRIDE] zeroed
        uint4* __restrict__ lutb,         // [NFT][SUB][CAPL]
        float4* __restrict__ ffwx,        // [NFT*SUB*CAPF]
        float4* __restrict__ ffwy,
        unsigned* __restrict__ ffmeta) {
    int bi = blockIdx.x * blockDim.x + threadIdx.x;
    if (bi >= NHALF) return;
    int sb = blockIdx.x & (SUB - 1);

    int      kind[2] = {0, 0};        // 0 none, 1 lut, 2 ff
    uint4    le[2];
    int      lsbk[2];
    float4   w1[2], w2[2];
    unsigned fbase[2];
    int      fcnt[2] = {0, 0};
    int      fsbk[2][4];
    unsigned fcxcy[2][4];

    // ---- Phase A: compute (both instances) ----
#pragma unroll
    for (int s = 0; s < 2; ++s) {
        int i = bi + s * NHALF;
        bool is_lut = luts[i] > 0;
        bool is_ff  = !is_lut && (ffs[i] > 0);
        if (!is_lut && !is_ff) continue;

        float px = pos[2 * i], py = pos[2 * i + 1];
        int lox, loy;
        float wx[K], wy[K];
        axis_weights4(px, NBX, lox, wx);
        axis_weights4(py, NBY, loy, wy);

        if (is_lut) {
            kind[s] = 1;
            unsigned qx[4] = { q10(wx[0]), q10(wx[1]), q10(wx[2]), q10(wx[3]) };
            unsigned qy[4] = { q10(wy[0]), q10(wy[1]), q10(wy[2]), q10(wy[3]) };
            int tx = ((int)px) >> 4, ty = ((int)py) >> 3;
            unsigned rx = (unsigned)(lox - tx * FTX + 2);   // [0,16]
            unsigned ry = (unsigned)(loy - ty * FTY + 2);   // [0,8]
            le[s].x = qx[0] | (qx[1] << 10) | (qx[2] << 20);
            le[s].y = qx[3] | (qy[0] << 10) | (qy[1] << 20);
            le[s].z = qy[2] | (qy[3] << 10);
            le[s].w = rx | (ry << 5);
            lsbk[s] = (tx * TGY + ty) * SUB + sb;
        } else {
            kind[s] = 2;
            w1[s] = make_float4(wx[0], wx[1], wx[2], wx[3]);
            w2[s] = make_float4(wy[0], wy[1], wy[2], wy[3]);
            fbase[s] = (unsigned)ctrl[2 * i] | ((48u + (unsigned)ctrl[2 * i + 1]) << 6);
            int tx0 = max(lox, 0) >> 4, tx1 = min(lox + 3, NBX - 1) >> 4;
            int ty0 = max(loy, 0) >> 3, ty1 = min(loy + 3, NBY - 1) >> 3;
            int n = 0;
            for (int tx = tx0; tx <= tx1; ++tx) {
                for (int ty = ty0; ty <= ty1; ++ty) {
                    unsigned cx = (unsigned)(lox - tx * FTX + 4);   // [1,19]
                    unsigned cy = (unsigned)(loy - ty * FTY + 4);   // [1,11]
                    fsbk[s][n]  = (tx * TGY + ty) * SUB + sb;
                    fcxcy[s][n] = (cx << 14) | (cy << 19);
                    ++n;
                }
            }
            fcnt[s] = n;
        }
    }

    // ---- Phase B: issue ALL atomics (independent; compiler pipelines) ----
    int lslot[2], fslot[2][4];
#pragma unroll
    for (int s = 0; s < 2; ++s)
        if (kind[s] == 1)
            lslot[s] = atomicAdd(&lut_cur[lsbk[s] * CSTRIDE], 1);
#pragma unroll
    for (int s = 0; s < 2; ++s)
#pragma unroll
        for (int t = 0; t < 4; ++t)
            if (kind[s] == 2 && t < fcnt[s])
                fslot[s][t] = atomicAdd(&ff_cur[fsbk[s][t] * CSTRIDE], 1);

    // ---- Phase C: dependent stores ----
#pragma unroll
    for (int s = 0; s < 2; ++s) {
        if (kind[s] == 1 && lslot[s] < CAPL)
            lutb[(size_t)lsbk[s] * CAPL + lslot[s]] = le[s];
#pragma unroll
        for (int t = 0; t < 4; ++t)
            if (kind[s] == 2 && t < fcnt[s] && fslot[s][t] < CAPF) {
                size_t idx = (size_t)fsbk[s][t] * CAPF + fslot[s][t];
                ffwx[idx] = w1[s];
                ffwy[idx] = w2[s];
                ffmeta[idx] = fbase[s] | fcxcy[s][t];
            }
    }
}

// Pass 2: pure decode + native LDS atomics; NO global atomics (patch -> plain store).
__global__ void __launch_bounds__(1024) tile_kernel(
        const uint4* __restrict__ lutb,
        const float4* __restrict__ ffwx,
        const float4* __restrict__ ffwy,
        const unsigned* __restrict__ ffmeta,
        const int* __restrict__ lut_cur,
        const int* __restrict__ ff_cur,
        unsigned* __restrict__ patch_g,   // [NFT][PW] fixed-point 2^20
        float* __restrict__ ff_scale) {
    __shared__ float acc[ACCW];
    __shared__ unsigned patch[PW];
    __shared__ int lpre[SUB + 1], fpre[SUB + 1];
    int t = blockIdx.x;
    int X0 = (t / TGY) * FTX;
    int Y0 = (t % TGY) * FTY;
    int tid = threadIdx.x;

    for (int j = tid; j < ACCW; j += 1024) acc[j] = 0.f;
    if (tid < PW) patch[tid] = 0u;
    if (tid == 0) {
        int s = 0; lpre[0] = 0;
        for (int c = 0; c < SUB; ++c) { s += min(lut_cur[(t * SUB + c) * CSTRIDE], CAPL); lpre[c + 1] = s; }
    } else if (tid == 1) {
        int s = 0; fpre[0] = 0;
        for (int c = 0; c < SUB; ++c) { s += min(ff_cur[(t * SUB + c) * CSTRIDE], CAPF); fpre[c + 1] = s; }
    }
    __syncthreads();

    int ltot = lpre[SUB];
    for (int e = tid; e < ltot; e += 1024) {
        int c = 0;
#pragma unroll
        for (int k = 1; k < SUB; ++k) c += (e >= lpre[k]);
        uint4 a = lutb[((size_t)t * SUB + c) * CAPL + (e - lpre[c])];
        unsigned qx[4] = { a.x & 1023u, (a.x >> 10) & 1023u, (a.x >> 20) & 1023u, a.y & 1023u };
        unsigned qy[4] = { (a.y >> 10) & 1023u, (a.y >> 20) & 1023u, a.z & 1023u, (a.z >> 10) & 1023u };
        int base = (int)(a.w & 31u) * PYW + (int)((a.w >> 5) & 15u);
#pragma unroll
        for (int kx = 0; kx < K; ++kx) {
            int rb = base + kx * PYW;
#pragma unroll
            for (int ky = 0; ky < K; ++ky)
                atomicAdd(&patch[rb + ky], qx[kx] * qy[ky]);   // ds_add_u32
        }
    }

    int ftot = fpre[SUB];
    for (int e = tid; e < ftot; e += 1024) {
        int c = 0;
#pragma unroll
        for (int k = 1; k < SUB; ++k) c += (e >= fpre[k]);
        size_t idx = ((size_t)t * SUB + c) * CAPF + (e - fpre[c]);
        float4 a = ffwx[idx];
        float4 b = ffwy[idx];
        unsigned m = ffmeta[idx];
        float fx[4] = { a.x, a.y, a.z, a.w };
        float fy[4] = { b.x, b.y, b.z, b.w };
        int ck   = (int)(m & 63u);
        int ce48 = (int)((m >> 6) & 255u);
        int cx   = (int)((m >> 14) & 31u) - 4;
        int cy   = (int)((m >> 19) & 15u) - 4;
#pragma unroll
        for (int kx = 0; kx < K; ++kx) {
            int gx = cx + kx;
            if ((unsigned)gx >= FTX) continue;
            float wv = fx[kx];
#pragma unroll
            for (int ky = 0; ky < K; ++ky) {
                int gy = cy + ky;
                if ((unsigned)gy >= FTY) continue;
                float w2 = wv * fy[ky];
                if (w2 != 0.f) {
                    float* row = acc + (gx * FTY + gy) * RS;
                    unsafeAtomicAdd(row + ck, w2);     // ds_add_f32
                    unsafeAtomicAdd(row + ce48, w2);
                }
            }
        }
    }
    __syncthreads();

    if (tid < 512) {
        int lb = tid >> 2, q = tid & 3;
        const float* row = acc + lb * RS;
        float raw = 0.f, effck = 0.f, effce = 0.f;
#pragma unroll
        for (int c = 0; c < 12; ++c) {
            float v = row[12 * q + c];
            raw += v;
            effck += ceilf(v * 0.125f);
        }
#pragma unroll
        for (int c = 0; c < 24; ++c) {
            effce += ceilf(row[48 + 24 * q + c] * 0.25f);
        }
        raw   += __shfl_xor(raw, 1);   raw   += __shfl_xor(raw, 2);
        effck += __shfl_xor(effck, 1); effck += __shfl_xor(effck, 2);
        effce += __shfl_xor(effce, 1); effce += __shfl_xor(effce, 2);
        if (q == 0) {
            float eff = fmaxf(effck * 8.f, effce * 4.f);
            int gx = X0 + (lb >> 3);
            int gy = Y0 + (lb & 7);
            ff_scale[gx * NBY + gy] = fmaxf(eff / fmaxf(raw, 1e-6f), 1.f);
        }
    } else if (tid < 512 + PW) {
        patch_g[(size_t)t * PW + (tid - 512)] = patch[tid - 512];   // plain store
    }
}

// Pass 2b: exact merge of overlapping patches -> lut_dem.
__global__ void __launch_bounds__(256) merge_kernel(
        const unsigned* __restrict__ patch_g,
        float* __restrict__ lut_dem) {
    int bin = blockIdx.x * 256 + threadIdx.x;
    int gx = bin / NBY, gy = bin % NBY;
    unsigned sum = 0u;
    int txc = gx >> 4, tyc = gy >> 3;
#pragma unroll
    for (int dx = -1; dx <= 1; ++dx) {
        int tx = txc + dx;
        if (tx < 0 || tx >= TGX) continue;
        int rx = gx - (tx * FTX - 2);
        if (rx < 0 || rx >= PXW) continue;
#pragma unroll
        for (int dy = -1; dy <= 1; ++dy) {
            int ty = tyc + dy;
            if (ty < 0 || ty >= TGY) continue;
            int ry = gy - (ty * FTY - 2);
            if (ry < 0 || ry >= PYW) continue;
            sum += patch_g[(size_t)(tx * TGY + ty) * PW + rx * PYW + ry];
        }
    }
    lut_dem[bin] = (float)sum * (1.f / 1048576.f);
}

// Pass 3: per-instance gather; recomputes exact f32 weights from pos.
__global__ void __launch_bounds__(256) area_kernel(
        const float* __restrict__ pos,
        const int* __restrict__ luts,
        const int* __restrict__ ffs,
        const float* __restrict__ lut_dem,
        const float* __restrict__ ff_scale,
        float* __restrict__ out) {
    int i = blockIdx.x * blockDim.x + threadIdx.x;
    if (i >= N_INST) return;
    bool is_lut = luts[i] > 0;
    bool is_ff  = (ffs[i] > 0) && !is_lut;
    if (!is_lut && !is_ff) { out[i] = 0.f; return; }

    float px = pos[2 * i], py = pos[2 * i + 1];
    int lox, loy;
    float wx[K], wy[K];
    axis_weights4(px, NBX, lox, wx);
    axis_weights4(py, NBY, loy, wy);

    const float* tbl = is_lut ? lut_dem : ff_scale;
    float acc = 0.f;
#pragma unroll
    for (int kx = 0; kx < K; ++kx) {
        int gx = min(max(lox + kx, 0), NBX - 1);
#pragma unroll
        for (int ky = 0; ky < K; ++ky) {
            int gy = min(max(loy + ky, 0), NBY - 1);
            float w2 = wx[kx] * wy[ky];
            float v = tbl[gx * NBY + gy];
            float sc = is_lut ? fmaxf(v * 0.0625f, 1.f) : v;
            acc += w2 * sc;
        }
    }
    out[i] = acc;
}

extern "C" void kernel_launch(void* const* d_in, const int* in_sizes, int n_in,
                              void* d_out, int out_size, void* d_ws, size_t ws_size,
                              hipStream_t stream) {
    const float* pos  = (const float*)d_in[0];
    const int*   luts = (const int*)d_in[1];
    const int*   ffs  = (const int*)d_in[2];
    const int*   ctrl = (const int*)d_in[3];
    float* out = (float*)d_out;

    // ws: lut_cur (1MB) | ff_cur (1MB) | lut_dem (1MB) | ff_scale (1MB) | patch_g (2MB)
    //     | lutb (25.2MB) | ffwx (12.6MB) | ffwy (12.6MB) | ffmeta (3.1MB)   ~60MB
    int*      lut_cur  = (int*)d_ws;
    int*      ff_cur   = lut_cur + NFT * SUB * CSTRIDE;
    float*    lut_dem  = (float*)(ff_cur + NFT * SUB * CSTRIDE);
    float*    ff_scale = lut_dem + NB;
    unsigned* patch_g  = (unsigned*)(ff_scale + NB);
    uint4*    lutb     = (uint4*)(patch_g + (size_t)NFT * PW);
    float4*   ffwx     = (float4*)(lutb + (size_t)NFT * SUB * CAPL);
    float4*   ffwy     = ffwx + (size_t)NFT * SUB * CAPF;
    unsigned* ffmeta   = (unsigned*)(ffwy + (size_t)NFT * SUB * CAPF);

    // Zero ONLY the cursors (2MB).
    hipMemsetAsync(d_ws, 0, (size_t)(2 * NFT * SUB * CSTRIDE) * sizeof(int), stream);

    dim3 blk(256);
    dim3 grdH((NHALF + 255) / 256);
    dim3 grdI((N_INST + 255) / 256);

    classify_kernel<<<grdH, blk, 0, stream>>>(pos, luts, ffs, ctrl,
                                              lut_cur, ff_cur, lutb, ffwx, ffwy, ffmeta);
    tile_kernel<<<NFT, dim3(1024), 0, stream>>>(lutb, ffwx, ffwy, ffmeta,
                                                lut_cur, ff_cur, patch_g, ff_scale);
    merge_kernel<<<NB / 256, blk, 0, stream>>>(patch_g, lut_dem);
    area_kernel<<<grdI, blk, 0, stream>>>(pos, luts, ffs, lut_dem, ff_scale, out);
}

// Round 21
// 126.389 us; speedup vs baseline: 1.0803x; 1.0803x over previous
//
#include <hip/hip_runtime.h>

#define N_INST   1000000
#define NBX      512
#define NBY      512
#define NB       (NBX * NBY)
#define NUM_CKSR 48
#define NUM_CE   96
#define K        4          // w[4] of the reference 5-tap is identically 0 (half = 1.5 exactly)

// R21 = R16 (best: 125.2us) + tile parallel cursor fetch. classify is pinned at the
// ~20 G returning-atomics/s device floor (947K atomics ~= 47us; R12-R20 invariant);
// tile's serial thread-0 prefix (8 dependent global loads, ~2.5us/block x 4 rounds)
// is the removable latency.
#define FTX   16
#define FTY   8
#define TGX   (NBX / FTX)   // 32
#define TGY   (NBY / FTY)   // 64
#define NFT   (TGX * TGY)   // 2048
#define SUB   8             // sub-buckets by blockIdx&7 (R13: single writer-XCD per line)
#define CAPL  96            // per sub-bucket; lut mean 43.6
#define CAPF  48            // per sub-bucket; ff mean 14.3 (dup 1.633)
#define RS    145           // 48 ck + 96 ce + pad (odd stride, conflict-free)
#define ACCW  (FTX * FTY * RS)      // 18560 words
#define PXW   20            // lut patch: x in [X0-2, X0+17]
#define PYW   12            // y in [Y0-2, Y0+9]
#define PW    (PXW * PYW)

#define CSTRIDE 16          // one cursor per 64B line (R5 lesson)

// Constants folded in DOUBLE then rounded once to f32 (matches JAX): half = 1.5f exactly.
#define KHALF  ((float)(2.5 * 0.6))
#define KDENOM ((float)(0.6 * 1.4142135623730951))

__device__ __forceinline__ void axis_weights4(float pos, int nbins, int& lo_out, float w[K]) {
    float wlo = pos - KHALF;
    float whi = pos + KHALF;
    int lo_bin = (int)floorf(wlo);
    lo_out = lo_bin;
    float phi[K + 1];
#pragma unroll
    for (int k = 0; k <= K; ++k) {
        float e = (float)(lo_bin + k);
        float ec = fminf(fmaxf(e, wlo), whi);
        phi[k] = 0.5f * (1.f + erff((ec - pos) / KDENOM));
    }
    float wsum = 0.f;
#pragma unroll
    for (int k = 0; k < K; ++k) {
        int b = lo_bin + k;
        float ww = phi[k + 1] - phi[k];
        if (b < 0 || b >= nbins) ww = 0.f;
        w[k] = ww;
        wsum += ww;
    }
    float d = wsum + 1e-12f;
#pragma unroll
    for (int k = 0; k < K; ++k) w[k] = w[k] / d;   // division, as in reference
}

__device__ __forceinline__ unsigned q10(float w) {   // plain u10 (lut path only; no ceil)
    return min(1023u, (unsigned)rintf(w * 1024.f));
}

// Pass 1 (R16 form): erf once; 1 instance/thread (TLP does the latency hiding, R20 lesson).
__global__ void __launch_bounds__(256) classify_kernel(
        const float* __restrict__ pos,
        const int* __restrict__ luts,
        const int* __restrict__ ffs,
        const int* __restrict__ ctrl,
        int* __restrict__ lut_cur,        // [NFT*SUB*CSTRIDE] zeroed
        int* __restrict__ ff_cur,         // [NFT*SUB*CSTRIDE] zeroed
        uint4* __restrict__ lutb,         // [NFT][SUB][CAPL]
        float4* __restrict__ ffwx,        // [NFT*SUB*CAPF]
        float4* __restrict__ ffwy,
        unsigned* __restrict__ ffmeta) {
    int i = blockIdx.x * blockDim.x + threadIdx.x;
    if (i >= N_INST) return;
    int sb = blockIdx.x & (SUB - 1);
    bool is_lut = luts[i] > 0;
    bool is_ff  = !is_lut && (ffs[i] > 0);
    if (!is_lut && !is_ff) return;

    float px = pos[2 * i], py = pos[2 * i + 1];
    int lox, loy;
    float wx[K], wy[K];
    axis_weights4(px, NBX, lox, wx);
    axis_weights4(py, NBY, loy, wy);

    if (is_lut) {
        unsigned qx[4] = { q10(wx[0]), q10(wx[1]), q10(wx[2]), q10(wx[3]) };
        unsigned qy[4] = { q10(wy[0]), q10(wy[1]), q10(wy[2]), q10(wy[3]) };
        int tx = ((int)px) >> 4, ty = ((int)py) >> 3;
        unsigned rx = (unsigned)(lox - tx * FTX + 2);   // [0,16]
        unsigned ry = (unsigned)(loy - ty * FTY + 2);   // [0,8]
        uint4 e;
        e.x = qx[0] | (qx[1] << 10) | (qx[2] << 20);
        e.y = qx[3] | (qy[0] << 10) | (qy[1] << 20);
        e.z = qy[2] | (qy[3] << 10);
        e.w = rx | (ry << 5);
        int sbk = (tx * TGY + ty) * SUB + sb;
        int slot = atomicAdd(&lut_cur[sbk * CSTRIDE], 1);
        if (slot < CAPL) lutb[(size_t)sbk * CAPL + slot] = e;
        return;
    }

    float4 w1 = make_float4(wx[0], wx[1], wx[2], wx[3]);
    float4 w2 = make_float4(wy[0], wy[1], wy[2], wy[3]);
    unsigned ck   = (unsigned)ctrl[2 * i];
    unsigned ce48 = 48u + (unsigned)ctrl[2 * i + 1];
    int tx0 = max(lox, 0) >> 4, tx1 = min(lox + 3, NBX - 1) >> 4;
    int ty0 = max(loy, 0) >> 3, ty1 = min(loy + 3, NBY - 1) >> 3;
    for (int tx = tx0; tx <= tx1; ++tx) {
        for (int ty = ty0; ty <= ty1; ++ty) {
            unsigned cx = (unsigned)(lox - tx * FTX + 4);   // [1,19]
            unsigned cy = (unsigned)(loy - ty * FTY + 4);   // [1,11]
            int sbk = (tx * TGY + ty) * SUB + sb;
            int slot = atomicAdd(&ff_cur[sbk * CSTRIDE], 1);
            if (slot < CAPF) {
                size_t idx = (size_t)sbk * CAPF + slot;
                ffwx[idx] = w1;
                ffwy[idx] = w2;
                ffmeta[idx] = ck | (ce48 << 6) | (cx << 14) | (cy << 19);
            }
        }
    }
}

// Pass 2: decode-only + native LDS atomics. Cursor fetch parallelized (16 threads,
// one global round-trip, latency hidden under acc init).
__global__ void __launch_bounds__(1024) tile_kernel(
        const uint4* __restrict__ lutb,
        const float4* __restrict__ ffwx,
        const float4* __restrict__ ffwy,
        const unsigned* __restrict__ ffmeta,
        const int* __restrict__ lut_cur,
        const int* __restrict__ ff_cur,
        float* __restrict__ lut_dem,
        float* __restrict__ ff_scale) {
    __shared__ float acc[ACCW];            // ff channel rows
    __shared__ unsigned patch[PW];         // lut demand, fixed-point 2^20
    __shared__ int cnt_s[2 * SUB];
    __shared__ int lpre[SUB + 1], fpre[SUB + 1];
    int t = blockIdx.x;
    int X0 = (t / TGY) * FTX;
    int Y0 = (t % TGY) * FTY;
    int tid = threadIdx.x;

    // Issue all 16 cursor loads first (independent, one latency round-trip).
    if (tid < SUB)
        cnt_s[tid] = min(lut_cur[(t * SUB + tid) * CSTRIDE], CAPL);
    else if (tid < 2 * SUB)
        cnt_s[tid] = min(ff_cur[(t * SUB + (tid - SUB)) * CSTRIDE], CAPF);

    for (int j = tid; j < ACCW; j += 1024) acc[j] = 0.f;   // covers cursor latency
    if (tid < PW) patch[tid] = 0u;
    __syncthreads();

    if (tid == 0) {
        int s = 0; lpre[0] = 0;
        for (int c = 0; c < SUB; ++c) { s += cnt_s[c]; lpre[c + 1] = s; }
    } else if (tid == 1) {
        int s = 0; fpre[0] = 0;
        for (int c = 0; c < SUB; ++c) { s += cnt_s[SUB + c]; fpre[c + 1] = s; }
    }
    __syncthreads();

    int ltot = lpre[SUB];
    for (int e = tid; e < ltot; e += 1024) {
        int c = 0;
#pragma unroll
        for (int k = 1; k < SUB; ++k) c += (e >= lpre[k]);
        uint4 a = lutb[((size_t)t * SUB + c) * CAPL + (e - lpre[c])];
        unsigned qx[4] = { a.x & 1023u, (a.x >> 10) & 1023u, (a.x >> 20) & 1023u, a.y & 1023u };
        unsigned qy[4] = { (a.y >> 10) & 1023u, (a.y >> 20) & 1023u, a.z & 1023u, (a.z >> 10) & 1023u };
        int base = (int)(a.w & 31u) * PYW + (int)((a.w >> 5) & 15u);
#pragma unroll
        for (int kx = 0; kx < K; ++kx) {
            int rb = base + kx * PYW;
#pragma unroll
            for (int ky = 0; ky < K; ++ky)
                atomicAdd(&patch[rb + ky], qx[kx] * qy[ky]);   // ds_add_u32
        }
    }

    int ftot = fpre[SUB];
    for (int e = tid; e < ftot; e += 1024) {
        int c = 0;
#pragma unroll
        for (int k = 1; k < SUB; ++k) c += (e >= fpre[k]);
        size_t idx = ((size_t)t * SUB + c) * CAPF + (e - fpre[c]);
        float4 a = ffwx[idx];
        float4 b = ffwy[idx];
        unsigned m = ffmeta[idx];
        float fx[4] = { a.x, a.y, a.z, a.w };
        float fy[4] = { b.x, b.y, b.z, b.w };
        int ck   = (int)(m & 63u);
        int ce48 = (int)((m >> 6) & 255u);
        int cx   = (int)((m >> 14) & 31u) - 4;
        int cy   = (int)((m >> 19) & 15u) - 4;
#pragma unroll
        for (int kx = 0; kx < K; ++kx) {
            int gx = cx + kx;
            if ((unsigned)gx >= FTX) continue;
            float wv = fx[kx];
#pragma unroll
            for (int ky = 0; ky < K; ++ky) {
                int gy = cy + ky;
                if ((unsigned)gy >= FTY) continue;
                float w2 = wv * fy[ky];
                if (w2 != 0.f) {
                    float* row = acc + (gx * FTY + gy) * RS;
                    unsafeAtomicAdd(row + ck, w2);     // ds_add_f32
                    unsafeAtomicAdd(row + ce48, w2);
                }
            }
        }
    }
    __syncthreads();

    if (tid < 512) {
        int lb = tid >> 2, q = tid & 3;
        const float* row = acc + lb * RS;
        float raw = 0.f, effck = 0.f, effce = 0.f;
#pragma unroll
        for (int c = 0; c < 12; ++c) {
            float v = row[12 * q + c];
            raw += v;
            effck += ceilf(v * 0.125f);
        }
#pragma unroll
        for (int c = 0; c < 24; ++c) {
            effce += ceilf(row[48 + 24 * q + c] * 0.25f);
        }
        raw   += __shfl_xor(raw, 1);   raw   += __shfl_xor(raw, 2);
        effck += __shfl_xor(effck, 1); effck += __shfl_xor(effck, 2);
        effce += __shfl_xor(effce, 1); effce += __shfl_xor(effce, 2);
        if (q == 0) {
            float eff = fmaxf(effck * 8.f, effce * 4.f);
            int gx = X0 + (lb >> 3);
            int gy = Y0 + (lb & 7);
            ff_scale[gx * NBY + gy] = fmaxf(eff / fmaxf(raw, 1e-6f), 1.f);
        }
    } else if (tid < 512 + PW) {
        // lut patch writeback (fire-and-forget: hidden, R19 lesson).
        int j = tid - 512;
        unsigned v = patch[j];
        if (v != 0u) {
            int gx = X0 - 2 + j / PYW;
            int gy = Y0 - 2 + j % PYW;
            if (gx >= 0 && gx < NBX && gy >= 0 && gy < NBY)
                unsafeAtomicAdd(&lut_dem[gx * NBY + gy], (float)v * (1.f / 1048576.f));
        }
    }
}

// Pass 3: per-instance gather; recomputes exact f32 weights from pos (R16).
__global__ void __launch_bounds__(256) area_kernel(
        const float* __restrict__ pos,
        const int* __restrict__ luts,
        const int* __restrict__ ffs,
        const float* __restrict__ lut_dem,
        const float* __restrict__ ff_scale,
        float* __restrict__ out) {
    int i = blockIdx.x * blockDim.x + threadIdx.x;
    if (i >= N_INST) return;
    bool is_lut = luts[i] > 0;
    bool is_ff  = (ffs[i] > 0) && !is_lut;
    if (!is_lut && !is_ff) { out[i] = 0.f; return; }

    float px = pos[2 * i], py = pos[2 * i + 1];
    int lox, loy;
    float wx[K], wy[K];
    axis_weights4(px, NBX, lox, wx);
    axis_weights4(py, NBY, loy, wy);

    const float* tbl = is_lut ? lut_dem : ff_scale;
    float acc = 0.f;
#pragma unroll
    for (int kx = 0; kx < K; ++kx) {
        int gx = min(max(lox + kx, 0), NBX - 1);
#pragma unroll
        for (int ky = 0; ky < K; ++ky) {
            int gy = min(max(loy + ky, 0), NBY - 1);
            float w2 = wx[kx] * wy[ky];
            float v = tbl[gx * NBY + gy];
            float sc = is_lut ? fmaxf(v * 0.0625f, 1.f) : v;
            acc += w2 * sc;
        }
    }
    out[i] = acc;
}

extern "C" void kernel_launch(void* const* d_in, const int* in_sizes, int n_in,
                              void* d_out, int out_size, void* d_ws, size_t ws_size,
                              hipStream_t stream) {
    const float* pos  = (const float*)d_in[0];
    const int*   luts = (const int*)d_in[1];
    const int*   ffs  = (const int*)d_in[2];
    const int*   ctrl = (const int*)d_in[3];
    float* out = (float*)d_out;

    // ws: lut_cur (1MB) | ff_cur (1MB) | lut_dem (1MB) | ff_scale (1MB)
    //     | lutb (25.2MB) | ffwx (12.6MB) | ffwy (12.6MB) | ffmeta (3.1MB)   ~58MB
    int*      lut_cur  = (int*)d_ws;
    int*      ff_cur   = lut_cur + NFT * SUB * CSTRIDE;
    float*    lut_dem  = (float*)(ff_cur + NFT * SUB * CSTRIDE);
    float*    ff_scale = lut_dem + NB;
    uint4*    lutb     = (uint4*)(ff_scale + NB);
    float4*   ffwx     = (float4*)(lutb + (size_t)NFT * SUB * CAPL);
    float4*   ffwy     = ffwx + (size_t)NFT * SUB * CAPF;
    unsigned* ffmeta   = (unsigned*)(ffwy + (size_t)NFT * SUB * CAPF);

    // Zero cursors + lut_dem (contiguous ~3MB). ff_scale fully written by tile_kernel.
    hipMemsetAsync(d_ws, 0, (size_t)(2 * NFT * SUB * CSTRIDE + NB) * sizeof(int), stream);

    dim3 blk(256);
    dim3 grdI((N_INST + 255) / 256);

    classify_kernel<<<grdI, blk, 0, stream>>>(pos, luts, ffs, ctrl,
                                              lut_cur, ff_cur, lutb, ffwx, ffwy, ffmeta);
    tile_kernel<<<NFT, dim3(1024), 0, stream>>>(lutb, ffwx, ffwy, ffmeta,
                                                lut_cur, ff_cur, lut_dem, ff_scale);
    area_kernel<<<grdI, blk, 0, stream>>>(pos, luts, ffs, lut_dem, ff_scale, out);
}